// Round 5
// baseline (2812.763 us; speedup 1.0000x reference)
//
#include <hip/hip_runtime.h>
#include <hip/hip_bf16.h>

// SRNN text encoder (all device inputs/outputs FP32):
//   Phase 0: convert weights -> bf16 in ws; gather+convert 256 used emb rows.
//   Phase 1: Gx[dir][b*32+t][2048] = Xemb @ Wih^T + (bih+bhh)   (fp32)
//   Phase 2 (R4 rewrite): ONE persistent kernel, 16 independent blocks.
//            Block (dir, rb) owns chains 32rb..32rb+31 end-to-end: h in LDS
//            (XOR-swizzled), C/S prefix-sums in registers, 32 internal steps
//            with __syncthreads only. MFMA transposed (A=Whh rows=units,
//            B=h rows=chains) so lane regs span 4 consecutive units ->
//            b64 LDS h-writes and b64 Apack snapshot stores.
//   Phase 3: out = Apack @ Wout^T + bout -> [3968][7680] fp32 (128x128 tiles,
//            global_load_lds + XOR-swizzled LDS, unchanged from R3).

#define BT __hip_bfloat16

typedef short bf16x8 __attribute__((ext_vector_type(8)));
typedef float f32x4 __attribute__((ext_vector_type(4)));
typedef unsigned long long u64;

__device__ __forceinline__ bf16x8 ld_frag(const BT* p) {
    return *reinterpret_cast<const bf16x8*>(p);
}
__device__ __forceinline__ f32x4 mfma16(bf16x8 a, bf16x8 b, f32x4 c) {
    return __builtin_amdgcn_mfma_f32_16x16x32_bf16(a, b, c, 0, 0, 0);
}
__device__ __forceinline__ float sigm(float x) { return 1.0f / (1.0f + __expf(-x)); }

__device__ __forceinline__ void async16(const BT* g, BT* l) {
    __builtin_amdgcn_global_load_lds(
        (const __attribute__((address_space(1))) unsigned int*)g,
        (__attribute__((address_space(3))) unsigned int*)l,
        16, 0, 0);
}

union B4 { BT b[4]; u64 u; };

// ---------------- Phase 0a: fp32 -> bf16 weight conversion ----------------
__global__ __launch_bounds__(256) void conv_kernel(
    const float* __restrict__ s0, const float* __restrict__ s1,
    const float* __restrict__ s2, const float* __restrict__ s3,
    const float* __restrict__ s4, BT* __restrict__ dbase)
{
    const int z = blockIdx.z;
    const float* src = (z == 0) ? s0 : (z == 1) ? s1 : (z == 2) ? s2 : (z == 3) ? s3 : s4;
    const int nel = (z == 4) ? 7864320 : 1048576;
    BT* dst = dbase + (long)z * 1048576;
    const int n4 = nel >> 2;
    for (int i = blockIdx.x * 256 + threadIdx.x; i < n4; i += gridDim.x * 256) {
        float4 v = reinterpret_cast<const float4*>(src)[i];
        B4 t;
        t.b[0] = __float2bfloat16(v.x); t.b[1] = __float2bfloat16(v.y);
        t.b[2] = __float2bfloat16(v.z); t.b[3] = __float2bfloat16(v.w);
        reinterpret_cast<u64*>(dst)[i] = t.u;
    }
}

// ---------------- Phase 0b: gather + convert embeddings ----------------
__global__ __launch_bounds__(256) void gather_kernel(
    const int* __restrict__ x, const float* __restrict__ emb, BT* __restrict__ Xemb)
{
    const int i = blockIdx.x * 256 + threadIdx.x;
    const int r = i >> 7;
    const int cq = i & 127;
    const long row = x[r];
    float4 v = reinterpret_cast<const float4*>(emb + row * 512)[cq];
    B4 t;
    t.b[0] = __float2bfloat16(v.x); t.b[1] = __float2bfloat16(v.y);
    t.b[2] = __float2bfloat16(v.z); t.b[3] = __float2bfloat16(v.w);
    reinterpret_cast<u64*>(Xemb + (long)r * 512)[cq] = t.u;
}

// ---------------- Phase 1: x-gates ----------------
__global__ __launch_bounds__(256) void gx_kernel(
    const BT* __restrict__ Xemb,
    const BT* __restrict__ WihF, const BT* __restrict__ WihB,
    const float* __restrict__ bih_f, const float* __restrict__ bhh_f,
    const float* __restrict__ bih_b, const float* __restrict__ bhh_b,
    float* __restrict__ Gx)
{
    const int dir = blockIdx.z;
    const BT* Wih = dir ? WihB : WihF;
    const float* bih = dir ? bih_b : bih_f;
    const float* bhh = dir ? bhh_b : bhh_f;
    float* G = Gx + (long)dir * 256 * 2048;

    const int tid = threadIdx.x;
    const int w = tid >> 6, lane = tid & 63;
    const int m = lane & 15, q = lane >> 4;
    const int r0 = blockIdx.x * 32;
    const int c0 = blockIdx.y * 128 + w * 32;

    const BT* a0p = Xemb + (long)(r0 + m) * 512 + q * 8;
    const BT* a1p = Xemb + (long)(r0 + 16 + m) * 512 + q * 8;
    const BT* b0p = Wih + (long)(c0 + m) * 512 + q * 8;
    const BT* b1p = Wih + (long)(c0 + 16 + m) * 512 + q * 8;

    f32x4 acc[2][2] = {};
    for (int k0 = 0; k0 < 512; k0 += 32) {
        bf16x8 a0 = ld_frag(a0p + k0);
        bf16x8 a1 = ld_frag(a1p + k0);
        bf16x8 b0 = ld_frag(b0p + k0);
        bf16x8 b1 = ld_frag(b1p + k0);
        acc[0][0] = mfma16(a0, b0, acc[0][0]);
        acc[0][1] = mfma16(a0, b1, acc[0][1]);
        acc[1][0] = mfma16(a1, b0, acc[1][0]);
        acc[1][1] = mfma16(a1, b1, acc[1][1]);
    }
    #pragma unroll
    for (int rt = 0; rt < 2; ++rt)
        #pragma unroll
        for (int ct = 0; ct < 2; ++ct)
            #pragma unroll
            for (int reg = 0; reg < 4; ++reg) {
                int r = r0 + rt * 16 + q * 4 + reg;
                int c = c0 + ct * 16 + m;
                G[(long)r * 2048 + c] = acc[rt][ct][reg] + bih[c] + bhh[c];
            }
}

// ---------------- Phase 2: persistent recurrence (R4) ----------------
// grid 16 blocks x 512 threads. Block bid: dir = bid>>3, rb = bid&7.
// Hcur LDS layout: row chain_l (0..31), unit u at byte
//   chain_l*1024 + (((u>>3) ^ (chain_l&7)) * 16) + (u&7)*2   (XOR chunk swizzle)
// Wave wv (0..7) owns units [wv*64, wv*64+64) x 4 gates x all 32 chains.
// MFMA: A = Whh rows (units, M-dim), B = h rows (chains, N-dim):
//   D row = q*4+reg -> unit, col = m -> chain; lane f32x4 = 4 consecutive units.
__global__ __launch_bounds__(512, 2) void rec_kernel(
    const BT* __restrict__ WhhF, const BT* __restrict__ WhhB,
    const float* __restrict__ Gx, BT* __restrict__ Apack)
{
    __shared__ BT Hcur[32 * 512];

    const int bid = blockIdx.x;
    const int dir = bid >> 3;
    const int rb  = bid & 7;
    const BT* W = dir ? WhhB : WhhF;
    const float* G = Gx + (long)dir * 256 * 2048;

    const int tid = threadIdx.x;
    const int wv = tid >> 6;
    const int lane = tid & 63;
    const int m = lane & 15, q = lane >> 4;

    {   // zero Hcur (32*512*2 B = 4096 u64)
        u64* p = reinterpret_cast<u64*>(Hcur);
        for (int i = tid; i < 4096; i += 512) p[i] = 0ull;
    }
    __syncthreads();

    // persistent per-lane cell state / prefix sums: slot si = ut*2+ct,
    // 4 consecutive units each (unit = wv*64 + ut*16 + q*4 + r, chain = ct*16+m)
    f32x4 Creg[8], Sreg[8];
    #pragma unroll
    for (int i = 0; i < 8; ++i) {
        Creg[i] = (f32x4){0.f, 0.f, 0.f, 0.f};
        Sreg[i] = (f32x4){0.f, 0.f, 0.f, 0.f};
    }

    for (int s = 4 * rb; s < 32; ++s) {
        f32x4 acc[4][4][2];   // [gate][ut][ct]
        #pragma unroll
        for (int g = 0; g < 4; ++g)
            #pragma unroll
            for (int ut = 0; ut < 4; ++ut)
                #pragma unroll
                for (int ct = 0; ct < 2; ++ct)
                    acc[g][ut][ct] = (f32x4){0.f, 0.f, 0.f, 0.f};

        #pragma unroll 2
        for (int kc = 0; kc < 16; ++kc) {
            bf16x8 hb[2];
            #pragma unroll
            for (int ct = 0; ct < 2; ++ct) {
                const int row = ct * 16 + m;
                const int phys = (kc * 4 + q) ^ (m & 7);
                hb[ct] = ld_frag(Hcur + row * 512 + phys * 8);
            }
            #pragma unroll
            for (int g = 0; g < 4; ++g)
                #pragma unroll
                for (int ut = 0; ut < 4; ++ut) {
                    bf16x8 wf = ld_frag(
                        W + (long)(g * 512 + wv * 64 + ut * 16 + m) * 512 + kc * 32 + q * 8);
                    acc[g][ut][0] = mfma16(wf, hb[0], acc[g][ut][0]);
                    acc[g][ut][1] = mfma16(wf, hb[1], acc[g][ut][1]);
                }
        }
        __syncthreads();   // all Hcur reads complete

        const int pos = dir ? (31 - s) : s;
        #pragma unroll
        for (int ut = 0; ut < 4; ++ut)
            #pragma unroll
            for (int ct = 0; ct < 2; ++ct) {
                const int chain_l = ct * 16 + m;
                const int chain = rb * 32 + chain_l;
                const int d = chain >> 3;
                const int b = chain & 7;
                if (d > s) continue;               // chain not yet active
                const int u0u = wv * 64 + ut * 16 + q * 4;
                const int si = ut * 2 + ct;
                const float* gxp = G + (long)(b * 32 + pos) * 2048 + u0u;
                const float4 gxi = *(const float4*)(gxp);
                const float4 gxf = *(const float4*)(gxp + 512);
                const float4 gxg = *(const float4*)(gxp + 1024);
                const float4 gxo = *(const float4*)(gxp + 1536);
                B4 hp;
                #pragma unroll
                for (int r = 0; r < 4; ++r) {
                    const float gi = acc[0][ut][ct][r] + ((const float*)&gxi)[r];
                    const float gf = acc[1][ut][ct][r] + ((const float*)&gxf)[r];
                    const float gg = acc[2][ut][ct][r] + ((const float*)&gxg)[r];
                    const float go = acc[3][ut][ct][r] + ((const float*)&gxo)[r];
                    const float cn = sigm(gf) * Creg[si][r] + sigm(gi) * tanhf(gg);
                    const float h = sigm(go) * tanhf(cn);
                    Creg[si][r] = cn;
                    Sreg[si][r] += h;
                    hp.b[r] = __float2bfloat16(h);
                }
                const int phys = (u0u >> 3) ^ (chain_l & 7);
                *reinterpret_cast<u64*>(Hcur + chain_l * 512 + phys * 8 + (u0u & 7)) = hp.u;
                const int k = s - d;               // span length - 1
                if (k >= 1) {
                    const int p_span = dir ? pos : d;
                    const int off = (k - 1) * 32 - ((k - 1) * k) / 2;
                    const float inv = 1.0f / (float)(k + 1);
                    B4 sp;
                    #pragma unroll
                    for (int r = 0; r < 4; ++r)
                        sp.b[r] = __float2bfloat16(Sreg[si][r] * inv);
                    *reinterpret_cast<u64*>(
                        Apack + (long)(b * 496 + off + p_span) * 1024 + dir * 512 + u0u) = sp.u;
                }
            }
        __syncthreads();   // h writes visible before next step's reads
    }
}

// ---------------- Phase 3: projection (unchanged from R3) ----------------
__global__ __launch_bounds__(256) void proj_kernel(
    const BT* __restrict__ Apack, const BT* __restrict__ Woutbf,
    const float* __restrict__ bout, float* __restrict__ out)
{
    __shared__ BT As[128 * 64];
    __shared__ BT Bs[128 * 64];

    const int tid = threadIdx.x;
    const int lane = tid & 63;
    const int wu = __builtin_amdgcn_readfirstlane(tid >> 6);
    const int m = lane & 15, q = lane >> 4;
    const int wr = wu >> 1, wc = wu & 1;
    const int r0 = blockIdx.x * 128;
    const int c0 = blockIdx.y * 128;

    const int srow = lane >> 3;
    const int schunk = (lane & 7) ^ srow;

    f32x4 acc[4][4] = {};

    for (int kc = 0; kc < 16; ++kc) {
        const int k0 = kc * 64;
        #pragma unroll
        for (int j = 0; j < 4; ++j) {
            const int L = wu * 4 + j;
            const int row = L * 8 + srow;
            async16(Apack + (long)(r0 + row) * 1024 + k0 + schunk * 8,
                    As + L * 512);
            async16(Woutbf + (long)(c0 + row) * 1024 + k0 + schunk * 8,
                    Bs + L * 512);
        }
        __syncthreads();
        #pragma unroll
        for (int ks = 0; ks < 2; ++ks) {
            const int slot = ((ks << 2) | q) ^ (m & 7);
            bf16x8 af[4], bf[4];
            #pragma unroll
            for (int t = 0; t < 4; ++t) {
                af[t] = ld_frag(As + (wr * 64 + t * 16 + m) * 64 + slot * 8);
                bf[t] = ld_frag(Bs + (wc * 64 + t * 16 + m) * 64 + slot * 8);
            }
            #pragma unroll
            for (int mt = 0; mt < 4; ++mt)
                #pragma unroll
                for (int nt = 0; nt < 4; ++nt)
                    acc[mt][nt] = mfma16(af[mt], bf[nt], acc[mt][nt]);
        }
        __syncthreads();
    }

    #pragma unroll
    for (int mt = 0; mt < 4; ++mt)
        #pragma unroll
        for (int nt = 0; nt < 4; ++nt)
            #pragma unroll
            for (int reg = 0; reg < 4; ++reg) {
                const int r = r0 + wr * 64 + mt * 16 + q * 4 + reg;
                const int c = c0 + wc * 64 + nt * 16 + m;
                out[(long)r * 7680 + c] = acc[mt][nt][reg] + bout[c];
            }
}

extern "C" void kernel_launch(void* const* d_in, const int* in_sizes, int n_in,
                              void* d_out, int out_size, void* d_ws, size_t ws_size,
                              hipStream_t stream) {
    const int*   x     = (const int*)d_in[0];
    const float* emb   = (const float*)d_in[2];
    const float* Wih_f = (const float*)d_in[3];
    const float* Whh_f = (const float*)d_in[4];
    const float* bih_f = (const float*)d_in[5];
    const float* bhh_f = (const float*)d_in[6];
    const float* Wih_b = (const float*)d_in[7];
    const float* Whh_b = (const float*)d_in[8];
    const float* bih_b = (const float*)d_in[9];
    const float* bhh_b = (const float*)d_in[10];
    const float* Wout  = (const float*)d_in[11];
    const float* bout  = (const float*)d_in[12];
    float* out = (float*)d_out;

    char* ws = (char*)d_ws;
    const long MB = 1 << 20;
    float* Gx    = (float*)(ws + 0);                  // 4 MiB
    BT*    Apack = (BT*)(ws + 7 * MB);                // 7.75 MiB
    BT*    Xemb  = (BT*)(ws + 7 * MB + 7936 * 1024);  // 256 KiB
    BT*    Wbf   = (BT*)(ws + 15 * MB);               // 23 MiB -> ends at 38 MiB
    BT*    WihF  = Wbf;
    BT*    WihB  = Wbf + 1048576;
    BT*    WhhF  = Wbf + 2 * 1048576;
    BT*    WhhB  = Wbf + 3 * 1048576;
    BT*    Woutb = Wbf + 4 * 1048576;

    conv_kernel<<<dim3(512, 1, 5), 256, 0, stream>>>(
        Wih_f, Wih_b, Whh_f, Whh_b, Wout, Wbf);
    gather_kernel<<<128, 256, 0, stream>>>(x, emb, Xemb);

    gx_kernel<<<dim3(8, 16, 2), 256, 0, stream>>>(
        Xemb, WihF, WihB, bih_f, bhh_f, bih_b, bhh_b, Gx);

    rec_kernel<<<16, 512, 0, stream>>>(WhhF, WhhB, Gx, Apack);

    proj_kernel<<<dim3(31, 60), 256, 0, stream>>>(Apack, Woutb, bout, out);
}

// Round 6
// 798.689 us; speedup vs baseline: 3.5217x; 3.5217x over previous
//
#include <hip/hip_runtime.h>
#include <hip/hip_bf16.h>

// SRNN text encoder (all device inputs/outputs FP32):
//   Phase 0: convert weights -> bf16 in ws; gather+convert 256 used emb rows.
//   Phase 1: Gx[dir][b*32+t][2048] = Xemb @ Wih^T + (bih+bhh)   (fp32)
//   Phase 2 (R5 rewrite): ONE persistent kernel, 256 blocks (1/CU).
//     Block (dir, ub 0..31, cb 0..3): LDS-resident Whh slice (16 units x 4
//     gates = 64 KB, loaded ONCE), owns 64 chains. Waves split chains (16
//     each -> no redundant h reads). W rows ordered [gate][unit] so lane
//     (m,q) acc tiles = all 4 gates for units U0+q*4..+3, chain w*16+m ->
//     no gate exchange; C/S prefix in registers. Steps separated by
//     double-buffered H in global + per-(dir,cb) 32-block device-scope
//     barrier (the only blocks that exchange h).
//   Phase 3: out = Apack @ Wout^T + bout -> [3968][7680] fp32 (128x128
//     tiles, global_load_lds + XOR swizzle, unchanged from R3).

#define BT __hip_bfloat16

typedef short bf16x8 __attribute__((ext_vector_type(8)));
typedef float f32x4 __attribute__((ext_vector_type(4)));
typedef unsigned long long u64;

__device__ __forceinline__ bf16x8 ld_frag(const BT* p) {
    return *reinterpret_cast<const bf16x8*>(p);
}
__device__ __forceinline__ f32x4 mfma16(bf16x8 a, bf16x8 b, f32x4 c) {
    return __builtin_amdgcn_mfma_f32_16x16x32_bf16(a, b, c, 0, 0, 0);
}
__device__ __forceinline__ float sigm(float x) { return 1.0f / (1.0f + __expf(-x)); }

__device__ __forceinline__ void async16(const BT* g, BT* l) {
    __builtin_amdgcn_global_load_lds(
        (const __attribute__((address_space(1))) unsigned int*)g,
        (__attribute__((address_space(3))) unsigned int*)l,
        16, 0, 0);
}

union B4 { BT b[4]; u64 u; };

// ---------------- Phase 0a: fp32 -> bf16 weight conversion ----------------
__global__ __launch_bounds__(256) void conv_kernel(
    const float* __restrict__ s0, const float* __restrict__ s1,
    const float* __restrict__ s2, const float* __restrict__ s3,
    const float* __restrict__ s4, BT* __restrict__ dbase)
{
    const int z = blockIdx.z;
    const float* src = (z == 0) ? s0 : (z == 1) ? s1 : (z == 2) ? s2 : (z == 3) ? s3 : s4;
    const int nel = (z == 4) ? 7864320 : 1048576;
    BT* dst = dbase + (long)z * 1048576;
    const int n4 = nel >> 2;
    for (int i = blockIdx.x * 256 + threadIdx.x; i < n4; i += gridDim.x * 256) {
        float4 v = reinterpret_cast<const float4*>(src)[i];
        B4 t;
        t.b[0] = __float2bfloat16(v.x); t.b[1] = __float2bfloat16(v.y);
        t.b[2] = __float2bfloat16(v.z); t.b[3] = __float2bfloat16(v.w);
        reinterpret_cast<u64*>(dst)[i] = t.u;
    }
}

// ---------------- Phase 0b: gather + convert embeddings ----------------
__global__ __launch_bounds__(256) void gather_kernel(
    const int* __restrict__ x, const float* __restrict__ emb, BT* __restrict__ Xemb)
{
    const int i = blockIdx.x * 256 + threadIdx.x;
    const int r = i >> 7;
    const int cq = i & 127;
    const long row = x[r];
    float4 v = reinterpret_cast<const float4*>(emb + row * 512)[cq];
    B4 t;
    t.b[0] = __float2bfloat16(v.x); t.b[1] = __float2bfloat16(v.y);
    t.b[2] = __float2bfloat16(v.z); t.b[3] = __float2bfloat16(v.w);
    reinterpret_cast<u64*>(Xemb + (long)r * 512)[cq] = t.u;
}

// ---------------- Phase 1: x-gates ----------------
__global__ __launch_bounds__(256) void gx_kernel(
    const BT* __restrict__ Xemb,
    const BT* __restrict__ WihF, const BT* __restrict__ WihB,
    const float* __restrict__ bih_f, const float* __restrict__ bhh_f,
    const float* __restrict__ bih_b, const float* __restrict__ bhh_b,
    float* __restrict__ Gx)
{
    const int dir = blockIdx.z;
    const BT* Wih = dir ? WihB : WihF;
    const float* bih = dir ? bih_b : bih_f;
    const float* bhh = dir ? bhh_b : bhh_f;
    float* G = Gx + (long)dir * 256 * 2048;

    const int tid = threadIdx.x;
    const int w = tid >> 6, lane = tid & 63;
    const int m = lane & 15, q = lane >> 4;
    const int r0 = blockIdx.x * 32;
    const int c0 = blockIdx.y * 128 + w * 32;

    const BT* a0p = Xemb + (long)(r0 + m) * 512 + q * 8;
    const BT* a1p = Xemb + (long)(r0 + 16 + m) * 512 + q * 8;
    const BT* b0p = Wih + (long)(c0 + m) * 512 + q * 8;
    const BT* b1p = Wih + (long)(c0 + 16 + m) * 512 + q * 8;

    f32x4 acc[2][2] = {};
    for (int k0 = 0; k0 < 512; k0 += 32) {
        bf16x8 a0 = ld_frag(a0p + k0);
        bf16x8 a1 = ld_frag(a1p + k0);
        bf16x8 b0 = ld_frag(b0p + k0);
        bf16x8 b1 = ld_frag(b1p + k0);
        acc[0][0] = mfma16(a0, b0, acc[0][0]);
        acc[0][1] = mfma16(a0, b1, acc[0][1]);
        acc[1][0] = mfma16(a1, b0, acc[1][0]);
        acc[1][1] = mfma16(a1, b1, acc[1][1]);
    }
    #pragma unroll
    for (int rt = 0; rt < 2; ++rt)
        #pragma unroll
        for (int ct = 0; ct < 2; ++ct)
            #pragma unroll
            for (int reg = 0; reg < 4; ++reg) {
                int r = r0 + rt * 16 + q * 4 + reg;
                int c = c0 + ct * 16 + m;
                G[(long)r * 2048 + c] = acc[rt][ct][reg] + bih[c] + bhh[c];
            }
}

// ---------------- Phase 2: persistent fused recurrence (R5) ----------------
// grid 256 x 256. bid: dir=bid>>7, sub=bid&127, ub=sub>>2 (0..31), cb=sub&3.
// Wlds: 64 rows (row = g*16 + (u-U0)) x 512, chunk-group layout:
//   elem addr = c_hi*4096 + row*64 + phys8*8,  phys8 = (chunk&7)^(row&7)
// A-frag (lane m,q; tile tA; kc): chunk=kc*4+q ->
//   Wlds + (chunk>>3)*4096 + (tA*16+m)*64 + ((chunk&7)^(m&7))*8
// D tile tA row q*4+r -> gate tA, unit U0+q*4+r; col m -> chain w*16+m.
// H double-buffered in global: in = H[s&1], out = H[(s+1)&1].
// Barrier group = (dir, cb): 32 blocks (exactly the h producers/consumers).
__global__ __launch_bounds__(256, 1) void rec_kernel(
    const BT* __restrict__ WhhF, const BT* __restrict__ WhhB,
    const float* __restrict__ Gx,
    BT* __restrict__ H, BT* __restrict__ Apack,
    unsigned int* __restrict__ bar)
{
    __shared__ BT Wlds[64 * 512];   // 64 KB

    const int bid = blockIdx.x;
    const int dir = bid >> 7, sub = bid & 127;
    const int ub = sub >> 2, cb = sub & 3;
    const BT* W = dir ? WhhB : WhhF;
    const float* G = Gx + (long)dir * 524288;

    const int tid = threadIdx.x;
    const int w = tid >> 6, lane = tid & 63;
    const int m = lane & 15, q = lane >> 4;
    const int sr = lane >> 3, sc = lane & 7;
    const int U0 = ub * 16;

    // ---- stage W slice into LDS (once): wave w covers c_hi = 2w, 2w+1 ----
    #pragma unroll
    for (int ci = 0; ci < 2; ++ci) {
        const int c_hi = w * 2 + ci;
        #pragma unroll
        for (int rg = 0; rg < 8; ++rg) {
            const int row = rg * 8 + sr;
            const int g = row >> 4, u = U0 + (row & 15);
            async16(W + (long)(g * 512 + u) * 512 + c_hi * 64 + (sc ^ sr) * 8,
                    Wlds + c_hi * 4096 + rg * 512);
        }
    }
    __syncthreads();

    const int mychain = cb * 64 + w * 16 + m;   // per-dir chain id (0..255)
    const int d = mychain >> 3, b = mychain & 7;
    unsigned int* barp = bar + (dir * 4 + cb) * 32;   // 128 B spacing

    f32x4 C = {0.f, 0.f, 0.f, 0.f};
    f32x4 S = {0.f, 0.f, 0.f, 0.f};
    unsigned int tgt = 0;

    for (int s = 0; s < 32; ++s) {
        if (cb * 8 <= s) {   // block has at least one active chain
            const BT* Hin = H + (s & 1) * 262144 + (long)(dir * 256 + mychain) * 512;
            f32x4 acc[4] = {};
            for (int kc = 0; kc < 16; ++kc) {
                bf16x8 hb = ld_frag(Hin + kc * 32 + q * 8);
                const int chunk = kc * 4 + q;
                const BT* wp = Wlds + (chunk >> 3) * 4096 + ((chunk & 7) ^ (m & 7)) * 8 + m * 64;
                acc[0] = mfma16(ld_frag(wp), hb, acc[0]);
                acc[1] = mfma16(ld_frag(wp + 1024), hb, acc[1]);
                acc[2] = mfma16(ld_frag(wp + 2048), hb, acc[2]);
                acc[3] = mfma16(ld_frag(wp + 3072), hb, acc[3]);
            }
            if (d <= s) {
                const int pos = dir ? (31 - s) : s;
                const float* gxp = G + (long)(b * 32 + pos) * 2048 + U0 + q * 4;
                const float4 gxi = *(const float4*)(gxp);
                const float4 gxf = *(const float4*)(gxp + 512);
                const float4 gxg = *(const float4*)(gxp + 1024);
                const float4 gxo = *(const float4*)(gxp + 1536);
                B4 hp;
                #pragma unroll
                for (int r = 0; r < 4; ++r) {
                    const float gi = acc[0][r] + ((const float*)&gxi)[r];
                    const float gf = acc[1][r] + ((const float*)&gxf)[r];
                    const float gg = acc[2][r] + ((const float*)&gxg)[r];
                    const float go = acc[3][r] + ((const float*)&gxo)[r];
                    const float cn = sigm(gf) * C[r] + sigm(gi) * tanhf(gg);
                    const float h = sigm(go) * tanhf(cn);
                    C[r] = cn;
                    S[r] += h;
                    hp.b[r] = __float2bfloat16(h);
                }
                BT* Hout = H + ((s + 1) & 1) * 262144;
                *reinterpret_cast<u64*>(
                    Hout + (long)(dir * 256 + mychain) * 512 + U0 + q * 4) = hp.u;
                const int k = s - d;
                if (k >= 1) {
                    const int p_span = dir ? pos : d;
                    const int off = (k - 1) * 32 - ((k - 1) * k) / 2;
                    const float inv = 1.0f / (float)(k + 1);
                    B4 sp;
                    #pragma unroll
                    for (int r = 0; r < 4; ++r)
                        sp.b[r] = __float2bfloat16(S[r] * inv);
                    *reinterpret_cast<u64*>(
                        Apack + (long)(b * 496 + off + p_span) * 1024
                              + dir * 512 + U0 + q * 4) = sp.u;
                }
            }
        }
        // ---- group barrier: 32 blocks sharing (dir, cb) ----
        __syncthreads();
        tgt += 32;
        if (tid == 0) {
            __threadfence();
            atomicAdd(barp, 1u);
            while (__hip_atomic_load(barp, __ATOMIC_RELAXED,
                                     __HIP_MEMORY_SCOPE_AGENT) < tgt)
                __builtin_amdgcn_s_sleep(2);
            __threadfence();
        }
        __syncthreads();
    }
}

// ---------------- Phase 3: projection (unchanged from R3) ----------------
__global__ __launch_bounds__(256) void proj_kernel(
    const BT* __restrict__ Apack, const BT* __restrict__ Woutbf,
    const float* __restrict__ bout, float* __restrict__ out)
{
    __shared__ BT As[128 * 64];
    __shared__ BT Bs[128 * 64];

    const int tid = threadIdx.x;
    const int lane = tid & 63;
    const int wu = __builtin_amdgcn_readfirstlane(tid >> 6);
    const int m = lane & 15, q = lane >> 4;
    const int wr = wu >> 1, wc = wu & 1;
    const int r0 = blockIdx.x * 128;
    const int c0 = blockIdx.y * 128;

    const int srow = lane >> 3;
    const int schunk = (lane & 7) ^ srow;

    f32x4 acc[4][4] = {};

    for (int kc = 0; kc < 16; ++kc) {
        const int k0 = kc * 64;
        #pragma unroll
        for (int j = 0; j < 4; ++j) {
            const int L = wu * 4 + j;
            const int row = L * 8 + srow;
            async16(Apack + (long)(r0 + row) * 1024 + k0 + schunk * 8,
                    As + L * 512);
            async16(Woutbf + (long)(c0 + row) * 1024 + k0 + schunk * 8,
                    Bs + L * 512);
        }
        __syncthreads();
        #pragma unroll
        for (int ks = 0; ks < 2; ++ks) {
            const int slot = ((ks << 2) | q) ^ (m & 7);
            bf16x8 af[4], bf[4];
            #pragma unroll
            for (int t = 0; t < 4; ++t) {
                af[t] = ld_frag(As + (wr * 64 + t * 16 + m) * 64 + slot * 8);
                bf[t] = ld_frag(Bs + (wc * 64 + t * 16 + m) * 64 + slot * 8);
            }
            #pragma unroll
            for (int mt = 0; mt < 4; ++mt)
                #pragma unroll
                for (int nt = 0; nt < 4; ++nt)
                    acc[mt][nt] = mfma16(af[mt], bf[nt], acc[mt][nt]);
        }
        __syncthreads();
    }

    #pragma unroll
    for (int mt = 0; mt < 4; ++mt)
        #pragma unroll
        for (int nt = 0; nt < 4; ++nt)
            #pragma unroll
            for (int reg = 0; reg < 4; ++reg) {
                const int r = r0 + wr * 64 + mt * 16 + q * 4 + reg;
                const int c = c0 + wc * 64 + nt * 16 + m;
                out[(long)r * 7680 + c] = acc[mt][nt][reg] + bout[c];
            }
}

extern "C" void kernel_launch(void* const* d_in, const int* in_sizes, int n_in,
                              void* d_out, int out_size, void* d_ws, size_t ws_size,
                              hipStream_t stream) {
    const int*   x     = (const int*)d_in[0];
    const float* emb   = (const float*)d_in[2];
    const float* Wih_f = (const float*)d_in[3];
    const float* Whh_f = (const float*)d_in[4];
    const float* bih_f = (const float*)d_in[5];
    const float* bhh_f = (const float*)d_in[6];
    const float* Wih_b = (const float*)d_in[7];
    const float* Whh_b = (const float*)d_in[8];
    const float* bih_b = (const float*)d_in[9];
    const float* bhh_b = (const float*)d_in[10];
    const float* Wout  = (const float*)d_in[11];
    const float* bout  = (const float*)d_in[12];
    float* out = (float*)d_out;

    char* ws = (char*)d_ws;
    const long MB = 1 << 20;
    float* Gx    = (float*)(ws + 0);                  // 4 MiB
    BT*    H     = (BT*)(ws + 4 * MB);                // 2 bufs x 512 KiB = 1 MiB
    unsigned int* bar = (unsigned int*)(ws + 5 * MB); // 8 counters x 128 B
    BT*    Apack = (BT*)(ws + 7 * MB);                // 7.75 MiB
    BT*    Xemb  = (BT*)(ws + 7 * MB + 7936 * 1024);  // 256 KiB
    BT*    Wbf   = (BT*)(ws + 15 * MB);               // 23 MiB -> ends at 38 MiB
    BT*    WihF  = Wbf;
    BT*    WihB  = Wbf + 1048576;
    BT*    WhhF  = Wbf + 2 * 1048576;
    BT*    WhhB  = Wbf + 3 * 1048576;
    BT*    Woutb = Wbf + 4 * 1048576;

    // zero H (both buffers) + barrier counters
    hipMemsetAsync(ws + 4 * MB, 0, MB + 4096, stream);

    conv_kernel<<<dim3(512, 1, 5), 256, 0, stream>>>(
        Wih_f, Wih_b, Whh_f, Whh_b, Wout, Wbf);
    gather_kernel<<<128, 256, 0, stream>>>(x, emb, Xemb);

    gx_kernel<<<dim3(8, 16, 2), 256, 0, stream>>>(
        Xemb, WihF, WihB, bih_f, bhh_f, bih_b, bhh_b, Gx);

    rec_kernel<<<256, 256, 0, stream>>>(WhhF, WhhB, Gx, H, Apack, bar);

    proj_kernel<<<dim3(31, 60), 256, 0, stream>>>(Apack, Woutb, bout, out);
}